// Round 5
// baseline (991.446 us; speedup 1.0000x reference)
//
#include <hip/hip_runtime.h>
#include <hip/hip_bf16.h>
#include <stdint.h>

#define DIM 384
#define QKVN 1152
#define NHEAD 12
#define HDIM 32
#define NTOK 49
#define NWIN 2048
static constexpr float SCALE_Q = 0.17677669529663687f;  // 32^-0.5

typedef float f32x4 __attribute__((ext_vector_type(4)));
typedef float f32x4u __attribute__((ext_vector_type(4), aligned(4)));
typedef __bf16 bf16x8 __attribute__((ext_vector_type(8)));
typedef unsigned short u16;
typedef u16 u16x8 __attribute__((ext_vector_type(8)));
typedef u16 u16x4 __attribute__((ext_vector_type(4)));

static __device__ __forceinline__ u16 f2bf(float f) {
  __hip_bfloat16 h = __float2bfloat16(f);
  return __builtin_bit_cast(unsigned short, h);
}
static __device__ __forceinline__ f32x4 mfma_bf16(u16x8 a, u16x8 b, f32x4 c) {
  return __builtin_amdgcn_mfma_f32_16x16x32_bf16(
      __builtin_bit_cast(bf16x8, a), __builtin_bit_cast(bf16x8, b), c, 0, 0, 0);
}

// ---------------- fp32 -> bf16 convert (n % 4 == 0) ----------------
__global__ void k_convert(const float* __restrict__ s, u16* __restrict__ d, int n) {
  int i = (blockIdx.x * 256 + threadIdx.x) * 4;
  if (i < n) {
    f32x4 v = *(const f32x4*)(s + i);
    u16x4 o;
    o[0] = f2bf(v[0]); o[1] = f2bf(v[1]); o[2] = f2bf(v[2]); o[3] = f2bf(v[3]);
    *(u16x4*)(d + i) = o;
  }
}

// ---------------- pos-bias table: [12][49][49] fp32 ----------------
__global__ void k_posbias(const float* __restrict__ w1, const float* __restrict__ b1,
                          const float* __restrict__ w2, const float* __restrict__ b2,
                          float* __restrict__ out) {
  int idx = blockIdx.x * 256 + threadIdx.x;
  if (idx >= NTOK * NTOK) return;
  int i = idx / NTOK, j = idx % NTOK;
  float d0 = (float)(j / 7 - i / 7);
  float d1 = (float)(j % 7 - i % 7);
  d0 = copysignf(log1pf(fabsf(d0)), d0);
  d1 = copysignf(log1pf(fabsf(d1)), d1);
  float acc[NHEAD];
#pragma unroll
  for (int o2 = 0; o2 < NHEAD; o2++) acc[o2] = b2[o2];
#pragma unroll 4
  for (int o = 0; o < 32; o++) {
    float h = fmaxf(d0 * w1[o * 2] + d1 * w1[o * 2 + 1] + b1[o], 0.f);
#pragma unroll
    for (int o2 = 0; o2 < NHEAD; o2++) acc[o2] += h * w2[o2 * 32 + o];
  }
#pragma unroll
  for (int o2 = 0; o2 < NHEAD; o2++) out[(o2 * NTOK + i) * NTOK + j] = acc[o2];
}

// ---------------- fused posb+mask: pbm[w][h][49][49] ----------------
__global__ void k_pbm(const float* __restrict__ posb, const float* __restrict__ mask,
                      float* __restrict__ pbm) {
  int idx = blockIdx.x * 256 + threadIdx.x;
  if (idx >= 64 * NHEAD * NTOK * NTOK) return;
  int j = idx % (NTOK * NTOK);
  int t = idx / (NTOK * NTOK);
  int h = t % NHEAD, w = t / NHEAD;
  pbm[idx] = posb[h * NTOK * NTOK + j] + mask[w * NTOK * NTOK + j];
}

// ---------------- GEMM: A-resident-in-LDS, zero inner barriers ----------------
// Block = 4 waves, owns 64 rows of A (full K=384 in LDS, 48 KB, XOR-swizzled).
// Loops bn over N in 128-col tiles; wave wv owns cols wv*32..+31 of each tile.
// B-fragments loaded global->reg (W is L2-resident), prefetched 1 k-step ahead.
// MODE 0: A = x fp32 (inline-convert), out = qkv bf16, cols<384 scaled by SCALE_Q
// MODE 1: A = attn_out bf16,           out = fp32 + proj_b
template <int MODE>
__global__ __launch_bounds__(256, 3) void k_gemm(const void* __restrict__ Ap,
                                                 const u16* __restrict__ Bw,
                                                 const float* __restrict__ bias,
                                                 void* __restrict__ Cp) {
  __shared__ u16 As[64 * 384];  // rows x (12 granules of 64B, 4 sub-segs swizzled)
  const int tid = threadIdx.x;
  const int bm = blockIdx.x;  // 0..1567, 64 rows each (100352 = 1568*64)
  const int lane = tid & 63, wv = tid >> 6;
  const int l15 = lane & 15, l4 = lane >> 4;

  // ---- stage A: 64 rows x 48 segs(16B); thread: row tid>>2, segs (tid&3)*12..+11
  {
    const int sr = tid >> 2;
    const int s0 = (tid & 3) * 12;
    if (MODE == 0) {
      const float* ap = (const float*)Ap + (size_t)(bm * 64 + sr) * DIM + s0 * 8;
      f32x4 f[24];
#pragma unroll
      for (int i = 0; i < 24; i++) f[i] = *(const f32x4*)(ap + i * 4);
#pragma unroll
      for (int s = 0; s < 12; s++) {
        u16x8 o;
#pragma unroll
        for (int j = 0; j < 4; j++) { o[j] = f2bf(f[2 * s][j]); o[j + 4] = f2bf(f[2 * s + 1][j]); }
        const int seg = s0 + s, g = seg >> 2, l = seg & 3;
        *(u16x8*)&As[sr * 384 + g * 32 + ((l ^ (sr & 3)) * 8)] = o;
      }
    } else {
      const u16* ap = (const u16*)Ap + (size_t)(bm * 64 + sr) * DIM + s0 * 8;
#pragma unroll
      for (int s = 0; s < 12; s++) {
        u16x8 v = *(const u16x8*)(ap + s * 8);
        const int seg = s0 + s, g = seg >> 2, l = seg & 3;
        *(u16x8*)&As[sr * 384 + g * 32 + ((l ^ (sr & 3)) * 8)] = v;
      }
    }
  }
  __syncthreads();  // the ONLY barrier

  const int NBN = (MODE == 0) ? 9 : 3;

  // B fragment base: col = bn*128 + wv*32 + n*16 + l15, k-offset l4*8
  const u16* bbase = Bw + (size_t)(wv * 32 + l15) * DIM + l4 * 8;

  u16x8 nb0 = *(const u16x8*)(bbase);
  u16x8 nb1 = *(const u16x8*)(bbase + 16 * DIM);

  for (int bn = 0; bn < NBN; ++bn) {
    f32x4 acc[4][2] = {};
    const u16* bcur = bbase + (size_t)bn * 128 * DIM;
#pragma unroll
    for (int it = 0; it < 12; ++it) {
      u16x8 b0 = nb0, b1 = nb1;
      if (it < 11) {
        nb0 = *(const u16x8*)(bcur + (it + 1) * 32);
        nb1 = *(const u16x8*)(bcur + 16 * DIM + (it + 1) * 32);
      } else if (bn + 1 < NBN) {
        const u16* bnx = bbase + (size_t)(bn + 1) * 128 * DIM;
        nb0 = *(const u16x8*)(bnx);
        nb1 = *(const u16x8*)(bnx + 16 * DIM);
      }
      u16x8 af[4];
#pragma unroll
      for (int m = 0; m < 4; m++) {
        const int r = m * 16 + l15;
        af[m] = *(const u16x8*)&As[r * 384 + it * 32 + ((l4 ^ (r & 3)) * 8)];
      }
#pragma unroll
      for (int m = 0; m < 4; m++) {
        acc[m][0] = mfma_bf16(af[m], b0, acc[m][0]);
        acc[m][1] = mfma_bf16(af[m], b1, acc[m][1]);
      }
    }
    // epilogue for this bn tile (no barrier; As untouched)
#pragma unroll
    for (int n = 0; n < 2; n++) {
      const int col = bn * 128 + wv * 32 + n * 16 + l15;
      const float bv = bias[col];
#pragma unroll
      for (int m = 0; m < 4; m++) {
        const int row0 = bm * 64 + m * 16 + l4 * 4;
#pragma unroll
        for (int r = 0; r < 4; r++) {
          float v = acc[m][n][r] + bv;
          if (MODE == 0) {
            if (col < DIM) v *= SCALE_Q;
            ((u16*)Cp)[(size_t)(row0 + r) * QKVN + col] = f2bf(v);
          } else {
            ((float*)Cp)[(size_t)(row0 + r) * DIM + col] = v;
          }
        }
      }
    }
  }
}

// ---------------- attention: 1 block = 1 window, 4 waves, pipelined 12-head loop ----------------
// Swapped QK^T: S^T = mfma(K_frag, Q_frag) puts a full score row (one q) per lane:
// row-max/sum are in-register + 2 shfl_xor across the l4 group.
__global__ __launch_bounds__(256) void k_attn(const u16* __restrict__ qkv,
                                              const float* __restrict__ pbm,
                                              u16* __restrict__ aout) {
  __shared__ u16 qs[2][64 * 32];   // q rows (swizzled segs; rows 49..63 zero)
  __shared__ u16 ks[2][64 * 32];   // k rows (swizzled)
  __shared__ u16 vts[2][32 * 72];  // v transposed [d][token], tokens 49..71 zero
  __shared__ u16 ps[64 * 72];      // P bf16 (wave-private row blocks)
  const int g = blockIdx.x;
  const int b = (((g >> 3) >> 3) << 6) + (g & 7) * 8 + ((g >> 3) & 7);
  const int w = b & 63;
  const int tid = threadIdx.x;
  const int lane = tid & 63, wv = tid >> 6;
  const int l15 = lane & 15, l4 = lane >> 4;
  const int fr = (l15 >> 1) & 3;

  for (int i = tid; i < 64 * 32; i += 256)
    if ((i >> 5) >= NTOK) { qs[0][i] = 0; qs[1][i] = 0; ks[0][i] = 0; ks[1][i] = 0; }
  for (int i = tid; i < 32 * 72; i += 256)
    if ((i % 72) >= NTOK) { vts[0][i] = 0; vts[1][i] = 0; }

  const int trow = tid >> 2, tseg = tid & 3;
  const int fT = (trow >> 1) & 3;
  u16x8 rq, rk, rv;

#define LOAD_REGS(h)                                                                 \
  if (tid < 196) {                                                                   \
    const u16* src = qkv + (size_t)(b * NTOK + trow) * QKVN + (h) * HDIM + tseg * 8; \
    rq = *(const u16x8*)src;                                                         \
    rk = *(const u16x8*)(src + DIM);                                                 \
    rv = *(const u16x8*)(src + 2 * DIM);                                             \
  }
#define WRITE_LDS(buf)                                                               \
  if (tid < 196) {                                                                   \
    *(u16x8*)&qs[buf][trow * 32 + (tseg ^ fT) * 8] = rq;                             \
    *(u16x8*)&ks[buf][trow * 32 + (tseg ^ fT) * 8] = rk;                             \
    _Pragma("unroll") for (int j = 0; j < 8; j++)                                    \
        vts[buf][(tseg * 8 + j) * 72 + trow] = rv[j];                                \
  }

  LOAD_REGS(0)
  WRITE_LDS(0)

  const int qrow = wv * 16 + l15;  // this lane's q-row in softmax phase
  const int qc = (qrow < NTOK) ? qrow : NTOK - 1;

  for (int h = 0; h < NHEAD; ++h) {
    const int buf = h & 1;
    if (h + 1 < NHEAD) LOAD_REGS(h + 1)
    __syncthreads();  // buf's writes (from prev iter) visible; prev compute done

    // S^T = K @ Q^T : wave wv owns q-cols (rows of S) wv*16..+15
    u16x8 bq = *(const u16x8*)&qs[buf][(wv * 16 + l15) * 32 + (l4 ^ fr) * 8];
    f32x4 s[4];
#pragma unroll
    for (int n = 0; n < 4; n++) {
      u16x8 ak = *(const u16x8*)&ks[buf][(n * 16 + l15) * 32 + (l4 ^ fr) * 8];
      f32x4 z = {0.f, 0.f, 0.f, 0.f};
      s[n] = mfma_bf16(ak, bq, z);  // lane: S[q=qrow][k = n*16 + l4*4 + r]
    }

    // softmax along k (fully in-lane + 2 shfls)
    const float* pr = pbm + ((size_t)(w * NHEAD + h) * NTOK + qc) * NTOK;
    float sv[4][4];
    float mx = -1e30f;
#pragma unroll
    for (int n = 0; n < 4; n++) {
      f32x4 p4 = *(const f32x4u*)(pr + n * 16 + l4 * 4);
#pragma unroll
      for (int r = 0; r < 4; r++) {
        const int k = n * 16 + l4 * 4 + r;
        float v = (k < NTOK) ? s[n][r] + p4[r] : -1e30f;
        sv[n][r] = v;
        mx = fmaxf(mx, v);
      }
    }
    mx = fmaxf(mx, __shfl_xor(mx, 16));
    mx = fmaxf(mx, __shfl_xor(mx, 32));
    float e[4][4], sum = 0.f;
#pragma unroll
    for (int n = 0; n < 4; n++)
#pragma unroll
      for (int r = 0; r < 4; r++) {
        const int k = n * 16 + l4 * 4 + r;
        e[n][r] = (k < NTOK) ? __expf(sv[n][r] - mx) : 0.f;
        sum += e[n][r];
      }
    sum += __shfl_xor(sum, 16);
    sum += __shfl_xor(sum, 32);
    const float inv = 1.0f / sum;
#pragma unroll
    for (int n = 0; n < 4; n++) {
      u16x4 pk;
#pragma unroll
      for (int r = 0; r < 4; r++) pk[r] = f2bf(e[n][r] * inv);
      *(u16x4*)&ps[qrow * 72 + n * 16 + l4 * 4] = pk;  // 8B packed write
    }
    // ps rows are wave-private: no barrier needed.

    // O = P @ V : K = 64 (2 steps), 32 cols (2 frags)
    f32x4 o[2] = {};
#pragma unroll
    for (int kk = 0; kk < 2; kk++) {
      u16x8 ap = *(const u16x8*)&ps[(wv * 16 + l15) * 72 + kk * 32 + l4 * 8];
#pragma unroll
      for (int n = 0; n < 2; n++) {
        u16x8 bvv = *(const u16x8*)&vts[buf][(n * 16 + l15) * 72 + kk * 32 + l4 * 8];
        o[n] = mfma_bf16(ap, bvv, o[n]);
      }
    }
#pragma unroll
    for (int n = 0; n < 2; n++) {
      const int col = n * 16 + l15;
#pragma unroll
      for (int r = 0; r < 4; r++) {
        const int row = wv * 16 + l4 * 4 + r;
        if (row < NTOK)
          aout[(size_t)(b * NTOK + row) * DIM + h * HDIM + col] = f2bf(o[n][r]);
      }
    }
    if (h + 1 < NHEAD) WRITE_LDS(buf ^ 1)  // disjoint from buf read this iter
  }
#undef LOAD_REGS
#undef WRITE_LDS
}

// ---------------- launch ----------------
extern "C" void kernel_launch(void* const* d_in, const int* in_sizes, int n_in,
                              void* d_out, int out_size, void* d_ws, size_t ws_size,
                              hipStream_t stream) {
  const float* x      = (const float*)d_in[0];
  const float* mask   = (const float*)d_in[1];
  const float* qkv_w  = (const float*)d_in[2];
  const float* qkv_b  = (const float*)d_in[3];
  const float* proj_w = (const float*)d_in[4];
  const float* proj_b = (const float*)d_in[5];
  const float* pm_w1  = (const float*)d_in[6];
  const float* pm_b1  = (const float*)d_in[7];
  const float* pm_w2  = (const float*)d_in[8];
  const float* pm_b2  = (const float*)d_in[9];
  float* out = (float*)d_out;

  char* ws = (char*)d_ws;
  u16*   qkv   = (u16*)(ws + 0);            // 100352*1152*2 = 231,211,008
  u16*   wqkv  = (u16*)(ws + 231211008);    //                     884,736
  u16*   wproj = (u16*)(ws + 232095744);    //                     294,912
  float* posb  = (float*)(ws + 232390656);  // 12*49*49*4    =     115,248
  float* pbm   = (float*)(ws + 232505904);  // 64*12*49*49*4 =   7,375,872
  u16*   aout  = (u16*)(ws + 239881776);    // 100352*384*2  =  77,070,336
  // total ws need: 316,952,112 bytes

  k_convert<<<432, 256, 0, stream>>>(qkv_w, wqkv, 442368);
  k_convert<<<144, 256, 0, stream>>>(proj_w, wproj, 147456);
  k_posbias<<<10, 256, 0, stream>>>(pm_w1, pm_b1, pm_w2, pm_b2, posb);
  k_pbm<<<7203, 256, 0, stream>>>(posb, mask, pbm);
  k_gemm<0><<<1568, 256, 0, stream>>>((const void*)x, wqkv, qkv_b, (void*)qkv);
  k_attn<<<2048, 256, 0, stream>>>(qkv, pbm, aout);
  k_gemm<1><<<1568, 256, 0, stream>>>((const void*)aout, wproj, proj_b, (void*)out);
}

// Round 6
// 669.979 us; speedup vs baseline: 1.4798x; 1.4798x over previous
//
#include <hip/hip_runtime.h>
#include <hip/hip_bf16.h>
#include <stdint.h>

#define DIM 384
#define QKVN 1152
#define NHEAD 12
#define HDIM 32
#define NTOK 49
#define NWIN 2048
static constexpr float SCALE_Q = 0.17677669529663687f;  // 32^-0.5

typedef float f32x4 __attribute__((ext_vector_type(4)));
typedef float f32x4u __attribute__((ext_vector_type(4), aligned(4)));
typedef __bf16 bf16x8 __attribute__((ext_vector_type(8)));
typedef unsigned short u16;
typedef u16 u16x8 __attribute__((ext_vector_type(8)));
typedef u16 u16x4 __attribute__((ext_vector_type(4)));

static __device__ __forceinline__ u16 f2bf(float f) {
  __hip_bfloat16 h = __float2bfloat16(f);
  return __builtin_bit_cast(unsigned short, h);
}
static __device__ __forceinline__ f32x4 mfma_bf16(u16x8 a, u16x8 b, f32x4 c) {
  return __builtin_amdgcn_mfma_f32_16x16x32_bf16(
      __builtin_bit_cast(bf16x8, a), __builtin_bit_cast(bf16x8, b), c, 0, 0, 0);
}

// ---------------- fp32 -> bf16 convert (n % 4 == 0) ----------------
__global__ void k_convert(const float* __restrict__ s, u16* __restrict__ d, int n) {
  int i = (blockIdx.x * 256 + threadIdx.x) * 4;
  if (i < n) {
    f32x4 v = *(const f32x4*)(s + i);
    u16x4 o;
    o[0] = f2bf(v[0]); o[1] = f2bf(v[1]); o[2] = f2bf(v[2]); o[3] = f2bf(v[3]);
    *(u16x4*)(d + i) = o;
  }
}

// ---------------- pos-bias table: [12][49][49] fp32 ----------------
__global__ void k_posbias(const float* __restrict__ w1, const float* __restrict__ b1,
                          const float* __restrict__ w2, const float* __restrict__ b2,
                          float* __restrict__ out) {
  int idx = blockIdx.x * 256 + threadIdx.x;
  if (idx >= NTOK * NTOK) return;
  int i = idx / NTOK, j = idx % NTOK;
  float d0 = (float)(j / 7 - i / 7);
  float d1 = (float)(j % 7 - i % 7);
  d0 = copysignf(log1pf(fabsf(d0)), d0);
  d1 = copysignf(log1pf(fabsf(d1)), d1);
  float acc[NHEAD];
#pragma unroll
  for (int o2 = 0; o2 < NHEAD; o2++) acc[o2] = b2[o2];
#pragma unroll 4
  for (int o = 0; o < 32; o++) {
    float h = fmaxf(d0 * w1[o * 2] + d1 * w1[o * 2 + 1] + b1[o], 0.f);
#pragma unroll
    for (int o2 = 0; o2 < NHEAD; o2++) acc[o2] += h * w2[o2 * 32 + o];
  }
#pragma unroll
  for (int o2 = 0; o2 < NHEAD; o2++) out[(o2 * NTOK + i) * NTOK + j] = acc[o2];
}

// ---------------- fused posb+mask: pbm[w][h][49][49] ----------------
__global__ void k_pbm(const float* __restrict__ posb, const float* __restrict__ mask,
                      float* __restrict__ pbm) {
  int idx = blockIdx.x * 256 + threadIdx.x;
  if (idx >= 64 * NHEAD * NTOK * NTOK) return;
  int j = idx % (NTOK * NTOK);
  int t = idx / (NTOK * NTOK);
  int h = t % NHEAD, w = t / NHEAD;
  pbm[idx] = posb[h * NTOK * NTOK + j] + mask[w * NTOK * NTOK + j];
}

// ---------------- GEMM: 128x128 tile, BK=64, dbuf LDS, ONE barrier per K-step ----
// LDS [row][64] u16, 16B segs XOR-swizzled: seg' = seg ^ (row&7)  (2-way max).
// Next-slab global loads issued BEFORE the barrier; consumed (LDS write) after
// the MFMA phase, so HBM/L2 latency hides under 32 MFMAs + 16 ds_reads.
// MODE 0: A = x fp32 (inline-convert), out = qkv bf16, cols<384 scaled by SCALE_Q
// MODE 1: A = attn_out bf16,           out = fp32 + proj_b
template <int MODE>
static __device__ __forceinline__ void gemm_body(const void* __restrict__ Ap,
                                                 const u16* __restrict__ Bw,
                                                 const float* __restrict__ bias,
                                                 void* __restrict__ Cp) {
  __shared__ u16 As[2][128 * 64];
  __shared__ u16 Bs[2][128 * 64];
  const int tid = threadIdx.x;
  const int NB = (MODE == 0) ? 9 : 3;
  const int PER = (MODE == 0) ? 882 : 294;  // gridDim.x / 8
  const int g = blockIdx.x;
  const int flat = (g & 7) * PER + (g >> 3);
  const int bm = flat / NB, bn = flat % NB;

  const int lane = tid & 63, wv = tid >> 6;
  const int wr = wv >> 1, wc = wv & 1;  // 2x2 waves, 64x64 each
  const int l15 = lane & 15, l4 = lane >> 4;
  const int sr = tid >> 1, hp = tid & 1;  // staging: row sr, k-half hp*32

  const float* a0 = (const float*)Ap + (size_t)(bm * 128 + sr) * DIM + hp * 32;
  const u16*   a1 = (const u16*)Ap + (size_t)(bm * 128 + sr) * DIM + hp * 32;
  const u16*   bb = Bw + (size_t)(bn * 128 + sr) * DIM + hp * 32;

  f32x4 fA[8];
  u16x8 rA[4], rB[4];

#define GLOAD(K0)                                                        \
  {                                                                      \
    if (MODE == 0) {                                                     \
      _Pragma("unroll") for (int i = 0; i < 8; i++)                      \
          fA[i] = *(const f32x4*)(a0 + (K0) + i * 4);                    \
    } else {                                                             \
      _Pragma("unroll") for (int i = 0; i < 4; i++)                      \
          rA[i] = *(const u16x8*)(a1 + (K0) + i * 8);                    \
    }                                                                    \
    _Pragma("unroll") for (int i = 0; i < 4; i++)                        \
        rB[i] = *(const u16x8*)(bb + (K0) + i * 8);                      \
  }

#define WLDS(BUF)                                                        \
  {                                                                      \
    _Pragma("unroll") for (int s = 0; s < 4; s++) {                      \
      u16x8 av;                                                          \
      if (MODE == 0) {                                                   \
        _Pragma("unroll") for (int j = 0; j < 4; j++) {                  \
          av[j] = f2bf(fA[2 * s][j]);                                    \
          av[j + 4] = f2bf(fA[2 * s + 1][j]);                            \
        }                                                                \
      } else av = rA[s];                                                 \
      const int st = ((hp * 4 + s) ^ (sr & 7)) * 8;                      \
      *(u16x8*)&As[BUF][sr * 64 + st] = av;                              \
      *(u16x8*)&Bs[BUF][sr * 64 + st] = rB[s];                           \
    }                                                                    \
  }

  GLOAD(0)
  WLDS(0)
  f32x4 acc[4][4] = {};

  for (int it = 0; it < 6; ++it) {
    const int cur = it & 1;
    if (it < 5) GLOAD((it + 1) * 64)  // issue next slab before the barrier
    __syncthreads();                  // cur-buffer writes visible
#pragma unroll
    for (int kk = 0; kk < 2; ++kk) {
      u16x8 af[4], bfr[4];
#pragma unroll
      for (int m = 0; m < 4; m++) {
        const int row = wr * 64 + m * 16 + l15;
        af[m] = *(const u16x8*)&As[cur][row * 64 + (((kk * 4 + l4) ^ (l15 & 7)) * 8)];
      }
#pragma unroll
      for (int n = 0; n < 4; n++) {
        const int row = wc * 64 + n * 16 + l15;
        bfr[n] = *(const u16x8*)&Bs[cur][row * 64 + (((kk * 4 + l4) ^ (l15 & 7)) * 8)];
      }
#pragma unroll
      for (int m = 0; m < 4; m++)
#pragma unroll
        for (int n = 0; n < 4; n++)
          acc[m][n] = mfma_bf16(af[m], bfr[n], acc[m][n]);
    }
    if (it < 5) WLDS(cur ^ 1)  // vmcnt wait lands here, after the MFMA phase
  }
#undef GLOAD
#undef WLDS

#pragma unroll
  for (int n = 0; n < 4; n++) {
    const int col = bn * 128 + wc * 64 + n * 16 + l15;
    const float bv = bias[col];
#pragma unroll
    for (int m = 0; m < 4; m++) {
      const int row0 = bm * 128 + wr * 64 + m * 16 + l4 * 4;
#pragma unroll
      for (int r = 0; r < 4; r++) {
        float v = acc[m][n][r] + bv;
        if (MODE == 0) {
          if (col < DIM) v *= SCALE_Q;
          ((u16*)Cp)[(size_t)(row0 + r) * QKVN + col] = f2bf(v);
        } else {
          ((float*)Cp)[(size_t)(row0 + r) * DIM + col] = v;
        }
      }
    }
  }
}

__global__ __launch_bounds__(256, 2) void k_qkv(const float* __restrict__ Ap,
                                                const u16* __restrict__ Bw,
                                                const float* __restrict__ bias,
                                                u16* __restrict__ Cp) {
  gemm_body<0>(Ap, Bw, bias, Cp);
}
__global__ __launch_bounds__(256, 2) void k_proj(const u16* __restrict__ Ap,
                                                 const u16* __restrict__ Bw,
                                                 const float* __restrict__ bias,
                                                 float* __restrict__ Cp) {
  gemm_body<1>(Ap, Bw, bias, Cp);
}

// ---------------- attention: 1 block = 1 window, 4 waves, pipelined 12-head loop ----------------
// Swapped QK^T: S^T = mfma(K_frag, Q_frag) puts a full score row (one q) per lane.
// pbm[w][h] slice staged coalesced into LDS (dbuf) -> no per-lane global gather.
__global__ __launch_bounds__(256) void k_attn(const u16* __restrict__ qkv,
                                              const float* __restrict__ pbm,
                                              u16* __restrict__ aout) {
  __shared__ u16 qs[2][64 * 32];    // q rows (swizzled segs; rows 49..63 zero)
  __shared__ u16 ks[2][64 * 32];    // k rows (swizzled)
  __shared__ u16 vts[2][32 * 72];   // v transposed [d][token], tokens 49..71 zero
  __shared__ float pbs[2][49 * 52 + 16];  // pbm slice, row stride 52 (+pad safety)
  __shared__ u16 ps[64 * 72];       // P bf16 (wave-private row blocks)
  const int g = blockIdx.x;
  const int b = (((g >> 3) >> 3) << 6) + (g & 7) * 8 + ((g >> 3) & 7);
  const int w = b & 63;
  const int tid = threadIdx.x;
  const int lane = tid & 63, wv = tid >> 6;
  const int l15 = lane & 15, l4 = lane >> 4;
  const int fr = (l15 >> 1) & 3;

  for (int i = tid; i < 64 * 32; i += 256)
    if ((i >> 5) >= NTOK) { qs[0][i] = 0; qs[1][i] = 0; ks[0][i] = 0; ks[1][i] = 0; }
  for (int i = tid; i < 32 * 72; i += 256)
    if ((i % 72) >= NTOK) { vts[0][i] = 0; vts[1][i] = 0; }

  const int trow = tid >> 2, tseg = tid & 3;
  const int fT = (trow >> 1) & 3;
  u16x8 rq, rk, rv;

  // pbm staging map: 49 rows x 13 float4 qwords = 637 items, <=3 per thread
  int psrc[3], pdst[3];
  bool pvld[3];
#pragma unroll
  for (int j = 0; j < 3; j++) {
    const int i = tid + j * 256;
    pvld[j] = i < 637;
    const int r = pvld[j] ? (i / 13) : 0;
    const int c = pvld[j] ? (i - r * 13) : 0;
    psrc[j] = r * 49 + c * 4;
    pdst[j] = r * 52 + c * 4;
  }
  f32x4u pb[3];

#define LOAD_REGS(h)                                                                 \
  {                                                                                  \
    if (tid < 196) {                                                                 \
      const u16* src = qkv + (size_t)(b * NTOK + trow) * QKVN + (h) * HDIM + tseg * 8; \
      rq = *(const u16x8*)src;                                                       \
      rk = *(const u16x8*)(src + DIM);                                               \
      rv = *(const u16x8*)(src + 2 * DIM);                                           \
    }                                                                                \
    const float* pbase = pbm + (size_t)(w * NHEAD + (h)) * (NTOK * NTOK);            \
    _Pragma("unroll") for (int j = 0; j < 3; j++)                                    \
        if (pvld[j]) pb[j] = *(const f32x4u*)(pbase + psrc[j]);                      \
  }
#define WRITE_LDS(buf)                                                               \
  {                                                                                  \
    if (tid < 196) {                                                                 \
      *(u16x8*)&qs[buf][trow * 32 + (tseg ^ fT) * 8] = rq;                           \
      *(u16x8*)&ks[buf][trow * 32 + (tseg ^ fT) * 8] = rk;                           \
      _Pragma("unroll") for (int j = 0; j < 8; j++)                                  \
          vts[buf][(tseg * 8 + j) * 72 + trow] = rv[j];                              \
    }                                                                                \
    _Pragma("unroll") for (int j = 0; j < 3; j++)                                    \
        if (pvld[j]) *(f32x4*)&pbs[buf][pdst[j]] = pb[j];                            \
  }

  LOAD_REGS(0)
  WRITE_LDS(0)

  const int qrow = wv * 16 + l15;  // this lane's q-row in softmax phase
  const int qc = (qrow < NTOK) ? qrow : NTOK - 1;

  for (int h = 0; h < NHEAD; ++h) {
    const int buf = h & 1;
    if (h + 1 < NHEAD) LOAD_REGS(h + 1)
    __syncthreads();  // buf's writes (from prev iter) visible; prev compute done

    // S^T = K @ Q^T : wave wv owns q-cols (rows of S) wv*16..+15
    u16x8 bq = *(const u16x8*)&qs[buf][(wv * 16 + l15) * 32 + (l4 ^ fr) * 8];
    f32x4 s[4];
#pragma unroll
    for (int n = 0; n < 4; n++) {
      u16x8 ak = *(const u16x8*)&ks[buf][(n * 16 + l15) * 32 + (l4 ^ fr) * 8];
      f32x4 z = {0.f, 0.f, 0.f, 0.f};
      s[n] = mfma_bf16(ak, bq, z);  // lane: S[q=qrow][k = n*16 + l4*4 + r]
    }

    // softmax along k (fully in-lane + 2 shfls); bias from LDS
    const float* pl = &pbs[buf][qc * 52];
    float sv[4][4];
    float mx = -1e30f;
#pragma unroll
    for (int n = 0; n < 4; n++) {
      f32x4 p4 = *(const f32x4*)(pl + n * 16 + l4 * 4);
#pragma unroll
      for (int r = 0; r < 4; r++) {
        const int k = n * 16 + l4 * 4 + r;
        float v = (k < NTOK) ? s[n][r] + p4[r] : -1e30f;
        sv[n][r] = v;
        mx = fmaxf(mx, v);
      }
    }
    mx = fmaxf(mx, __shfl_xor(mx, 16));
    mx = fmaxf(mx, __shfl_xor(mx, 32));
    float e[4][4], sum = 0.f;
#pragma unroll
    for (int n = 0; n < 4; n++)
#pragma unroll
      for (int r = 0; r < 4; r++) {
        const int k = n * 16 + l4 * 4 + r;
        e[n][r] = (k < NTOK) ? __expf(sv[n][r] - mx) : 0.f;
        sum += e[n][r];
      }
    sum += __shfl_xor(sum, 16);
    sum += __shfl_xor(sum, 32);
    const float inv = 1.0f / sum;
#pragma unroll
    for (int n = 0; n < 4; n++) {
      u16x4 pk;
#pragma unroll
      for (int r = 0; r < 4; r++) pk[r] = f2bf(e[n][r] * inv);
      *(u16x4*)&ps[qrow * 72 + n * 16 + l4 * 4] = pk;  // 8B packed write
    }
    // ps rows are wave-private: no barrier needed.

    // O = P @ V : K = 64 (2 steps), 32 cols (2 frags)
    f32x4 o[2] = {};
#pragma unroll
    for (int kk = 0; kk < 2; kk++) {
      u16x8 ap = *(const u16x8*)&ps[(wv * 16 + l15) * 72 + kk * 32 + l4 * 8];
#pragma unroll
      for (int n = 0; n < 2; n++) {
        u16x8 bvv = *(const u16x8*)&vts[buf][(n * 16 + l15) * 72 + kk * 32 + l4 * 8];
        o[n] = mfma_bf16(ap, bvv, o[n]);
      }
    }
#pragma unroll
    for (int n = 0; n < 2; n++) {
      const int col = n * 16 + l15;
#pragma unroll
      for (int r = 0; r < 4; r++) {
        const int row = wv * 16 + l4 * 4 + r;
        if (row < NTOK)
          aout[(size_t)(b * NTOK + row) * DIM + h * HDIM + col] = f2bf(o[n][r]);
      }
    }
    if (h + 1 < NHEAD) WRITE_LDS(buf ^ 1)  // disjoint from buf read this iter
  }
#undef LOAD_REGS
#undef WRITE_LDS
}

// ---------------- launch ----------------
extern "C" void kernel_launch(void* const* d_in, const int* in_sizes, int n_in,
                              void* d_out, int out_size, void* d_ws, size_t ws_size,
                              hipStream_t stream) {
  const float* x      = (const float*)d_in[0];
  const float* mask   = (const float*)d_in[1];
  const float* qkv_w  = (const float*)d_in[2];
  const float* qkv_b  = (const float*)d_in[3];
  const float* proj_w = (const float*)d_in[4];
  const float* proj_b = (const float*)d_in[5];
  const float* pm_w1  = (const float*)d_in[6];
  const float* pm_b1  = (const float*)d_in[7];
  const float* pm_w2  = (const float*)d_in[8];
  const float* pm_b2  = (const float*)d_in[9];
  float* out = (float*)d_out;

  char* ws = (char*)d_ws;
  u16*   qkv   = (u16*)(ws + 0);            // 100352*1152*2 = 231,211,008
  u16*   wqkv  = (u16*)(ws + 231211008);    //                     884,736
  u16*   wproj = (u16*)(ws + 232095744);    //                     294,912
  float* posb  = (float*)(ws + 232390656);  // 12*49*49*4    =     115,248
  float* pbm   = (float*)(ws + 232505904);  // 64*12*49*49*4 =   7,375,872
  u16*   aout  = (u16*)(ws + 239881776);    // 100352*384*2  =  77,070,336
  // total ws need: 316,952,112 bytes

  k_convert<<<432, 256, 0, stream>>>(qkv_w, wqkv, 442368);
  k_convert<<<144, 256, 0, stream>>>(proj_w, wproj, 147456);
  k_posbias<<<10, 256, 0, stream>>>(pm_w1, pm_b1, pm_w2, pm_b2, posb);
  k_pbm<<<7203, 256, 0, stream>>>(posb, mask, pbm);
  k_qkv<<<7056, 256, 0, stream>>>(x, wqkv, qkv_b, qkv);
  k_attn<<<2048, 256, 0, stream>>>(qkv, pbm, aout);
  k_proj<<<2352, 256, 0, stream>>>(aout, wproj, proj_b, out);
}